// Round 1
// baseline (2849.403 us; speedup 1.0000x reference)
//
#include <hip/hip_runtime.h>
#include <hip/hip_bf16.h>

#define NH 32
#define NKV 8
#define HD 64
#define SEQ 1024
#define BATCH 4
#define HDIM 2048

// ---------------- classic 128x128x8 fp32 SGEMM, 256 thr, 8x8 micro-tile ----
// scatter=1: C written as [b, head, s, d] (head = col/64, d = col%64)
// scatter=0: plain row-major C[M][N]
__global__ __launch_bounds__(256) void sgemm_k(
    const float* __restrict__ A, const float* __restrict__ B,
    float* __restrict__ C, int M, int N, int K, int scatter, int nheads)
{
  __shared__ float As[8][128];
  __shared__ float Bs[8][128];
  const int tid = threadIdx.x;
  const int tx = tid & 15, ty = tid >> 4;
  const int row0 = blockIdx.y * 128;
  const int col0 = blockIdx.x * 128;

  const int aRow = tid >> 1, aCol = (tid & 1) * 4;
  const int bRow = tid >> 5, bCol = (tid & 31) * 4;

  const float* Ap = A + (long)(row0 + aRow) * K + aCol;
  const float* Bp = B + (long)bRow * N + col0 + bCol;

  float acc[8][8] = {};
  for (int k0 = 0; k0 < K; k0 += 8) {
    float4 av = *(const float4*)Ap;
    float4 bv = *(const float4*)Bp;
    As[aCol + 0][aRow] = av.x;
    As[aCol + 1][aRow] = av.y;
    As[aCol + 2][aRow] = av.z;
    As[aCol + 3][aRow] = av.w;
    *(float4*)&Bs[bRow][bCol] = bv;
    __syncthreads();
#pragma unroll
    for (int k = 0; k < 8; ++k) {
      float ar[8], br[8];
#pragma unroll
      for (int i = 0; i < 8; ++i) ar[i] = As[k][ty * 8 + i];
#pragma unroll
      for (int j = 0; j < 8; ++j) br[j] = Bs[k][tx * 8 + j];
#pragma unroll
      for (int i = 0; i < 8; ++i)
#pragma unroll
        for (int j = 0; j < 8; ++j) acc[i][j] += ar[i] * br[j];
    }
    __syncthreads();
    Ap += 8;
    Bp += (long)8 * N;
  }
#pragma unroll
  for (int i = 0; i < 8; ++i) {
    int row = row0 + ty * 8 + i;
    int b = row >> 10;   // row / SEQ
    int s = row & 1023;  // row % SEQ
#pragma unroll
    for (int j = 0; j < 8; ++j) {
      int col = col0 + tx * 8 + j;
      if (scatter) {
        int h = col >> 6, d = col & 63;
        C[(((long)(b * nheads + h)) * SEQ + s) * HD + d] = acc[i][j];
      } else {
        C[(long)row * N + col] = acc[i][j];
      }
    }
  }
}

// ---------------- RoPE in-place: one 64-lane wave per (b,h,s) row ----------
__global__ __launch_bounds__(64) void rope_k(
    float* __restrict__ t, const float* __restrict__ cs,
    const float* __restrict__ sn, int nheads)
{
  long row = blockIdx.x;  // (b*nheads + h)*SEQ + s
  int d = threadIdx.x;
  int s = (int)(row & 1023);
  int b = (int)(row / ((long)nheads * SEQ));
  float v = t[row * HD + d];
  float p = __shfl_xor(v, 32);            // partner element d^32
  float rh = (d < 32) ? -p : p;           // rotate_half
  long ci = ((long)b * SEQ + s) * HD + d;
  t[row * HD + d] = v * cs[ci] + rh * sn[ci];
}

// ---------------- scores: 64x64 tile of Q·K^T*scale + causal mask ---------
__global__ __launch_bounds__(256) void scores_k(
    const float* __restrict__ Q, const float* __restrict__ Kb,
    float* __restrict__ aw)
{
  const int bh = blockIdx.z;
  const int h = bh & 31, b = bh >> 5;
  const int kvh = h >> 2;  // GQA: 4 query heads per kv head
  const float* Qp = Q + (long)bh * SEQ * HD;
  const float* Kp = Kb + (long)(b * NKV + kvh) * SEQ * HD;
  const int q0 = blockIdx.y * 64, k0 = blockIdx.x * 64;
  __shared__ float Qs[64][65];  // [d][qi], transposed
  __shared__ float Ks[64][65];  // [d][ki], transposed
  const int tid = threadIdx.x;
  const int lr = tid >> 2, lc = (tid & 3) * 16;
#pragma unroll
  for (int u = 0; u < 16; u += 4) {
    float4 qv = *(const float4*)(Qp + (long)(q0 + lr) * HD + lc + u);
    float4 kv = *(const float4*)(Kp + (long)(k0 + lr) * HD + lc + u);
    Qs[lc + u + 0][lr] = qv.x; Qs[lc + u + 1][lr] = qv.y;
    Qs[lc + u + 2][lr] = qv.z; Qs[lc + u + 3][lr] = qv.w;
    Ks[lc + u + 0][lr] = kv.x; Ks[lc + u + 1][lr] = kv.y;
    Ks[lc + u + 2][lr] = kv.z; Ks[lc + u + 3][lr] = kv.w;
  }
  __syncthreads();
  const int tx = tid & 15, ty = tid >> 4;
  float acc[4][4] = {};
#pragma unroll 8
  for (int d = 0; d < 64; ++d) {
    float qr[4], kr[4];
#pragma unroll
    for (int i = 0; i < 4; ++i) qr[i] = Qs[d][ty * 4 + i];
#pragma unroll
    for (int j = 0; j < 4; ++j) kr[j] = Ks[d][tx * 4 + j];
#pragma unroll
    for (int i = 0; i < 4; ++i)
#pragma unroll
      for (int j = 0; j < 4; ++j) acc[i][j] += qr[i] * kr[j];
  }
  float* outp = aw + ((long)bh * SEQ + q0) * SEQ + k0;
#pragma unroll
  for (int i = 0; i < 4; ++i) {
    int qi = q0 + ty * 4 + i;
#pragma unroll
    for (int j = 0; j < 4; ++j) {
      int ki = k0 + tx * 4 + j;
      outp[(long)(ty * 4 + i) * SEQ + tx * 4 + j] =
          acc[i][j] * 0.125f + (qi >= ki ? 0.f : -1e9f);
    }
  }
}

// ---------------- softmax in place: one 256-thr block per row -------------
__global__ __launch_bounds__(256) void softmax_k(float* __restrict__ aw)
{
  long row = blockIdx.x;
  float* p = aw + row * SEQ;
  int tid = threadIdx.x;
  float4 v = *(float4*)(p + tid * 4);
  float m = fmaxf(fmaxf(v.x, v.y), fmaxf(v.z, v.w));
#pragma unroll
  for (int o = 32; o > 0; o >>= 1) m = fmaxf(m, __shfl_xor(m, o));
  __shared__ float redm[4];
  __shared__ float reds[4];
  if ((tid & 63) == 0) redm[tid >> 6] = m;
  __syncthreads();
  m = fmaxf(fmaxf(redm[0], redm[1]), fmaxf(redm[2], redm[3]));
  v.x = __expf(v.x - m); v.y = __expf(v.y - m);
  v.z = __expf(v.z - m); v.w = __expf(v.w - m);
  float ssum = v.x + v.y + v.z + v.w;
#pragma unroll
  for (int o = 32; o > 0; o >>= 1) ssum += __shfl_xor(ssum, o);
  if ((tid & 63) == 0) reds[tid >> 6] = ssum;
  __syncthreads();
  ssum = reds[0] + reds[1] + reds[2] + reds[3];
  float inv = 1.0f / ssum;
  v.x *= inv; v.y *= inv; v.z *= inv; v.w *= inv;
  *(float4*)(p + tid * 4) = v;
}

// ---------------- PV: ctx[b,s,h*64+d] = aw @ V (64x64 tiles, BK=32) -------
__global__ __launch_bounds__(256) void pv_k(
    const float* __restrict__ aw, const float* __restrict__ V,
    float* __restrict__ ctx)
{
  const int bh = blockIdx.y;
  const int h = bh & 31, b = bh >> 5;
  const int kvh = h >> 2;
  const int q0 = blockIdx.x * 64;
  const float* Ap = aw + ((long)bh * SEQ + q0) * SEQ;
  const float* Vp = V + (long)(b * NKV + kvh) * SEQ * HD;
  __shared__ float As[32][65];  // [k][qi], transposed
  __shared__ float Vs[32][64];  // [k][d]
  const int tid = threadIdx.x;
  const int tx = tid & 15, ty = tid >> 4;
  const int ar = tid >> 2, ac = (tid & 3) * 8;
  const int vr = tid >> 3, vc = (tid & 7) * 8;
  float acc[4][4] = {};
  for (int kk = 0; kk < SEQ; kk += 32) {
    float4 a0 = *(const float4*)(Ap + (long)ar * SEQ + kk + ac);
    float4 a1 = *(const float4*)(Ap + (long)ar * SEQ + kk + ac + 4);
    As[ac + 0][ar] = a0.x; As[ac + 1][ar] = a0.y;
    As[ac + 2][ar] = a0.z; As[ac + 3][ar] = a0.w;
    As[ac + 4][ar] = a1.x; As[ac + 5][ar] = a1.y;
    As[ac + 6][ar] = a1.z; As[ac + 7][ar] = a1.w;
    float4 v0 = *(const float4*)(Vp + (long)(kk + vr) * HD + vc);
    float4 v1 = *(const float4*)(Vp + (long)(kk + vr) * HD + vc + 4);
    *(float4*)&Vs[vr][vc] = v0;
    *(float4*)&Vs[vr][vc + 4] = v1;
    __syncthreads();
#pragma unroll
    for (int k = 0; k < 32; ++k) {
      float a4[4], v4[4];
#pragma unroll
      for (int i = 0; i < 4; ++i) a4[i] = As[k][ty * 4 + i];
#pragma unroll
      for (int j = 0; j < 4; ++j) v4[j] = Vs[k][tx * 4 + j];
#pragma unroll
      for (int i = 0; i < 4; ++i)
#pragma unroll
        for (int j = 0; j < 4; ++j) acc[i][j] += a4[i] * v4[j];
    }
    __syncthreads();
  }
#pragma unroll
  for (int i = 0; i < 4; ++i) {
    int s = q0 + ty * 4 + i;
#pragma unroll
    for (int j = 0; j < 4; ++j) {
      ctx[((long)b * SEQ + s) * HDIM + h * HD + tx * 4 + j] = acc[i][j];
    }
  }
}

extern "C" void kernel_launch(void* const* d_in, const int* in_sizes, int n_in,
                              void* d_out, int out_size, void* d_ws, size_t ws_size,
                              hipStream_t stream) {
  const float* x  = (const float*)d_in[0];
  const float* cs = (const float*)d_in[1];
  const float* sn = (const float*)d_in[2];
  // d_in[3]: attention_mask — causal, computed analytically instead
  const float* Wq = (const float*)d_in[4];
  const float* Wk = (const float*)d_in[5];
  const float* Wv = (const float*)d_in[6];
  const float* Wo = (const float*)d_in[7];

  float* out = (float*)d_out;                       // [B,S,H]
  float* aw  = out + (long)BATCH * SEQ * HDIM;      // [B,NH,S,S]

  float* ws  = (float*)d_ws;
  float* Q   = ws;                                  // [B,NH,S,HD]  8.4M floats
  float* Kb  = Q  + (long)BATCH * NH  * SEQ * HD;   // [B,NKV,S,HD] 2.1M
  float* V   = Kb + (long)BATCH * NKV * SEQ * HD;   // [B,NKV,S,HD] 2.1M
  float* ctx = V  + (long)BATCH * NKV * SEQ * HD;   // [B,S,H]      8.4M

  const int M = BATCH * SEQ;  // 4096

  // projections (scatter epilogue writes [b,head,s,d] directly)
  sgemm_k<<<dim3(2048 / 128, M / 128), 256, 0, stream>>>(x, Wq, Q,  M, 2048, HDIM, 1, NH);
  sgemm_k<<<dim3(512  / 128, M / 128), 256, 0, stream>>>(x, Wk, Kb, M, 512,  HDIM, 1, NKV);
  sgemm_k<<<dim3(512  / 128, M / 128), 256, 0, stream>>>(x, Wv, V,  M, 512,  HDIM, 1, NKV);

  // RoPE on Q and K
  rope_k<<<BATCH * NH  * SEQ, 64, 0, stream>>>(Q,  cs, sn, NH);
  rope_k<<<BATCH * NKV * SEQ, 64, 0, stream>>>(Kb, cs, sn, NKV);

  // raw masked scores -> aw region of d_out, then softmax in place
  scores_k<<<dim3(SEQ / 64, SEQ / 64, BATCH * NH), 256, 0, stream>>>(Q, Kb, aw);
  softmax_k<<<BATCH * NH * SEQ, 256, 0, stream>>>(aw);

  // PV with transpose-fused epilogue -> ctx [b,s,h*64+d]
  pv_k<<<dim3(SEQ / 64, BATCH * NH), 256, 0, stream>>>(aw, V, ctx);

  // output projection (plain row-major)
  sgemm_k<<<dim3(2048 / 128, M / 128), 256, 0, stream>>>(ctx, Wo, out, M, 2048, HDIM, 0, 0);
}

// Round 2
// 1351.642 us; speedup vs baseline: 2.1081x; 2.1081x over previous
//
#include <hip/hip_runtime.h>
#include <hip/hip_bf16.h>

#define NHQ 32
#define NKV 8
#define SEQ 1024
#define BATCH 4
#define HDIM 2048

typedef short bf16x8 __attribute__((ext_vector_type(8)));
typedef short short4v __attribute__((ext_vector_type(4)));
typedef float f32x4 __attribute__((ext_vector_type(4)));

__device__ __forceinline__ short f2bf(float f) {
  unsigned u = __builtin_bit_cast(unsigned, f);
  u += 0x7fff + ((u >> 16) & 1);
  return (short)(u >> 16);
}
__device__ __forceinline__ float bf2f(short s) {
  unsigned u = ((unsigned)(unsigned short)s) << 16;
  return __builtin_bit_cast(float, u);
}
__device__ __forceinline__ void gl2lds16(const void* g, void* l) {
  __builtin_amdgcn_global_load_lds(
      (const __attribute__((address_space(1))) unsigned int*)g,
      (__attribute__((address_space(3))) unsigned int*)l, 16, 0, 0);
}

// ---------- fp32 -> bf16 bulk convert (x) ----------
__global__ __launch_bounds__(256) void convx_k(
    const float* __restrict__ x, short* __restrict__ xb)
{
  long i = ((long)blockIdx.x * 256 + threadIdx.x) * 4;
  float4 v = *(const float4*)(x + i);
  short4v o = {f2bf(v.x), f2bf(v.y), f2bf(v.z), f2bf(v.w)};
  *(short4v*)(xb + i) = o;
}

// ---------- weight transpose fp32 [K][N] -> bf16 [N][K] ----------
__global__ __launch_bounds__(256) void wtrans_k(
    const float* __restrict__ W, short* __restrict__ WT, int K, int N)
{
  __shared__ float t[64][65];
  int k0 = blockIdx.y * 64, n0 = blockIdx.x * 64;
  int r = threadIdx.x >> 4, c = (threadIdx.x & 15) * 4;
#pragma unroll
  for (int it = 0; it < 4; ++it) {
    float4 v = *(const float4*)(W + (long)(k0 + r + it * 16) * N + n0 + c);
    t[c + 0][r + it * 16] = v.x;
    t[c + 1][r + it * 16] = v.y;
    t[c + 2][r + it * 16] = v.z;
    t[c + 3][r + it * 16] = v.w;
  }
  __syncthreads();
  int wr = threadIdx.x >> 2, wc = (threadIdx.x & 3) * 16;
#pragma unroll
  for (int u = 0; u < 4; ++u) {
    short4v o = {f2bf(t[wr][wc + u * 4 + 0]), f2bf(t[wr][wc + u * 4 + 1]),
                 f2bf(t[wr][wc + u * 4 + 2]), f2bf(t[wr][wc + u * 4 + 3])};
    *(short4v*)&WT[(long)(n0 + wr) * K + k0 + wc + u * 4] = o;
  }
}

// ---------- MFMA GEMM: C[M,N] = A[M,K] * BT[N,K]^T (bf16 in) ----------
// mode 0: C fp32 row-major [M][N]
// mode 1: C bf16 scatter [b, head, s, d]   (head = col/64, d = col%64)
// mode 2: C bf16 transpose-scatter [b, kvh, d, s]
__global__ __launch_bounds__(256) void gemm_k(
    const short* __restrict__ A, const short* __restrict__ BT,
    void* __restrict__ C, int M, int N, int K, int mode, int nheads)
{
  __shared__ short smA[128 * 32];
  __shared__ short smB[128 * 32];
  const int tid = threadIdx.x;
  const int lane = tid & 63, w = tid >> 6;
  const int wr = w >> 1, wc = w & 1;
  const int lm = lane & 15, lk = lane >> 4;
  const int row0 = blockIdx.y * 128, col0 = blockIdx.x * 128;
  const int c0 = tid, c1 = tid + 256;

  const short* Ab = A + (long)row0 * K;
  const short* Bb = BT + (long)col0 * K;

  f32x4 acc[4][4] = {};

  for (int k0 = 0; k0 < K; k0 += 32) {
    gl2lds16(Ab + (long)(c0 >> 2) * K + k0 + (c0 & 3) * 8, &smA[c0 * 8]);
    gl2lds16(Ab + (long)(c1 >> 2) * K + k0 + (c1 & 3) * 8, &smA[c1 * 8]);
    gl2lds16(Bb + (long)(c0 >> 2) * K + k0 + (c0 & 3) * 8, &smB[c0 * 8]);
    gl2lds16(Bb + (long)(c1 >> 2) * K + k0 + (c1 & 3) * 8, &smB[c1 * 8]);
    __syncthreads();
    bf16x8 af[4], bf[4];
#pragma unroll
    for (int i = 0; i < 4; ++i)
      af[i] = *(const bf16x8*)&smA[(wr * 64 + i * 16 + lm) * 32 + lk * 8];
#pragma unroll
    for (int j = 0; j < 4; ++j)
      bf[j] = *(const bf16x8*)&smB[(wc * 64 + j * 16 + lm) * 32 + lk * 8];
#pragma unroll
    for (int i = 0; i < 4; ++i)
#pragma unroll
      for (int j = 0; j < 4; ++j)
        acc[i][j] = __builtin_amdgcn_mfma_f32_16x16x32_bf16(af[i], bf[j], acc[i][j], 0, 0, 0);
    __syncthreads();
  }

#pragma unroll
  for (int i = 0; i < 4; ++i) {
    int grow = row0 + wr * 64 + i * 16 + lk * 4;  // + r
#pragma unroll
    for (int j = 0; j < 4; ++j) {
      int gcol = col0 + wc * 64 + j * 16 + lm;
      if (mode == 0) {
        float* Co = (float*)C;
#pragma unroll
        for (int r = 0; r < 4; ++r)
          Co[(long)(grow + r) * N + gcol] = acc[i][j][r];
      } else if (mode == 1) {
        short* Co = (short*)C;
        int h = gcol >> 6, d = gcol & 63;
#pragma unroll
        for (int r = 0; r < 4; ++r) {
          int row = grow + r;
          int b = row >> 10, s = row & 1023;
          Co[((long)(b * nheads + h) * SEQ + s) * 64 + d] = f2bf(acc[i][j][r]);
        }
      } else {
        short* Co = (short*)C;
        int kvh = gcol >> 6, d = gcol & 63;
        int b = grow >> 10, s0 = grow & 1023;
        short4v o = {f2bf(acc[i][j][0]), f2bf(acc[i][j][1]),
                     f2bf(acc[i][j][2]), f2bf(acc[i][j][3])};
        *(short4v*)&Co[((long)(b * NKV + kvh) * 64 + d) * SEQ + s0] = o;
      }
    }
  }
}

// ---------- RoPE in-place on bf16 [b,h,s,d], one wave per row ----------
__global__ __launch_bounds__(64) void rope_k(
    short* __restrict__ t, const float* __restrict__ cs,
    const float* __restrict__ sn, int nheads)
{
  long row = blockIdx.x;
  int d = threadIdx.x;
  int s = (int)(row & 1023);
  int b = (int)(row / ((long)nheads << 10));
  float v = bf2f(t[row * 64 + d]);
  float p = __shfl_xor(v, 32);
  float rh = (d < 32) ? -p : p;
  long ci = ((long)(b << 10) + s) * 64 + d;
  t[row * 64 + d] = f2bf(v * cs[ci] + rh * sn[ci]);
}

// ---------- scores: raw masked scaled QK^T via MFMA, direct-global frags --
__global__ __launch_bounds__(256) void scores_k(
    const short* __restrict__ Qb, const short* __restrict__ Kb,
    float* __restrict__ aw)
{
  const int bh = blockIdx.z;
  const int h = bh & 31, b = bh >> 5;
  const short* Qp = Qb + ((long)bh << 16);
  const short* Kp = Kb + ((long)(b * NKV + (h >> 2)) << 16);
  const int q0 = blockIdx.y * 128, k0 = blockIdx.x * 128;
  const int lane = threadIdx.x & 63, w = threadIdx.x >> 6;
  const int wr = w >> 1, wc = w & 1;
  const int lm = lane & 15, lk = lane >> 4;

  f32x4 acc[4][4] = {};
  bf16x8 qa[4][2], kb[4][2];
#pragma unroll
  for (int i = 0; i < 4; ++i)
#pragma unroll
    for (int kd = 0; kd < 2; ++kd)
      qa[i][kd] = *(const bf16x8*)(Qp + (long)(q0 + wr * 64 + i * 16 + lm) * 64 + kd * 32 + lk * 8);
#pragma unroll
  for (int j = 0; j < 4; ++j)
#pragma unroll
    for (int kd = 0; kd < 2; ++kd)
      kb[j][kd] = *(const bf16x8*)(Kp + (long)(k0 + wc * 64 + j * 16 + lm) * 64 + kd * 32 + lk * 8);
#pragma unroll
  for (int i = 0; i < 4; ++i)
#pragma unroll
    for (int j = 0; j < 4; ++j)
#pragma unroll
      for (int kd = 0; kd < 2; ++kd)
        acc[i][j] = __builtin_amdgcn_mfma_f32_16x16x32_bf16(qa[i][kd], kb[j][kd], acc[i][j], 0, 0, 0);

  float* Co = aw + ((long)bh << 20);
#pragma unroll
  for (int i = 0; i < 4; ++i)
#pragma unroll
    for (int j = 0; j < 4; ++j) {
      int ki = k0 + wc * 64 + j * 16 + lm;
#pragma unroll
      for (int r = 0; r < 4; ++r) {
        int qi = q0 + wr * 64 + i * 16 + lk * 4 + r;
        Co[(long)qi * SEQ + ki] = acc[i][j][r] * 0.125f + (qi >= ki ? 0.f : -1e9f);
      }
    }
}

// ---------- fused softmax + PV: aw := softmax(aw); ctxb = aw @ V ----------
__global__ __launch_bounds__(256) void smpv_k(
    float* __restrict__ aw, const short* __restrict__ Vt,
    short* __restrict__ ctxb)
{
  __shared__ short Pt[64 * 32];
  const int bh = blockIdx.y;
  const int h = bh & 31, b = bh >> 5;
  const int q0 = blockIdx.x * 64;
  float* Sp = aw + ((long)bh << 20) + (long)q0 * SEQ;
  const short* Vp = Vt + ((long)(b * NKV + (h >> 2)) << 16);  // [64 d][1024 s]
  const int tid = threadIdx.x;
  const int row = tid >> 2, qd = tid & 3;
  float* rp = Sp + (long)row * SEQ;

  // phase A: online row max + exp-sum (each thread 256 cols, stride-16 interleave)
  float m = -3.0e38f, l = 0.f;
  for (int i = 0; i < 64; ++i) {
    float4 v = *(const float4*)(rp + qd * 4 + i * 16);
    float mx = fmaxf(fmaxf(v.x, v.y), fmaxf(v.z, v.w));
    if (mx > m) { l *= __expf(m - mx); m = mx; }
    l += __expf(v.x - m) + __expf(v.y - m) + __expf(v.z - m) + __expf(v.w - m);
  }
#pragma unroll
  for (int off = 1; off <= 2; off <<= 1) {
    float mo = __shfl_xor(m, off), lo = __shfl_xor(l, off);
    float mn = fmaxf(m, mo);
    l = l * __expf(m - mn) + lo * __expf(mo - mn);
    m = mn;
  }
  float invl = 1.f / l;

  // phase B: normalize+write aw, P->LDS, PV MFMA
  const int lane = tid & 63, wv = tid >> 6;
  f32x4 oacc[4] = {};
  for (int kt = 0; kt < SEQ; kt += 32) {
    float4 v0 = *(const float4*)(rp + kt + qd * 8);
    float4 v1 = *(const float4*)(rp + kt + qd * 8 + 4);
    float p0 = __expf(v0.x - m) * invl, p1 = __expf(v0.y - m) * invl;
    float p2 = __expf(v0.z - m) * invl, p3 = __expf(v0.w - m) * invl;
    float p4 = __expf(v1.x - m) * invl, p5 = __expf(v1.y - m) * invl;
    float p6 = __expf(v1.z - m) * invl, p7 = __expf(v1.w - m) * invl;
    *(float4*)(rp + kt + qd * 8) = make_float4(p0, p1, p2, p3);
    *(float4*)(rp + kt + qd * 8 + 4) = make_float4(p4, p5, p6, p7);
    short4v s0 = {f2bf(p0), f2bf(p1), f2bf(p2), f2bf(p3)};
    short4v s1 = {f2bf(p4), f2bf(p5), f2bf(p6), f2bf(p7)};
    *(short4v*)&Pt[row * 32 + qd * 8] = s0;
    *(short4v*)&Pt[row * 32 + qd * 8 + 4] = s1;
    __syncthreads();
    bf16x8 pa = *(const bf16x8*)&Pt[(wv * 16 + (lane & 15)) * 32 + (lane >> 4) * 8];
#pragma unroll
    for (int dt = 0; dt < 4; ++dt) {
      bf16x8 vb = *(const bf16x8*)(Vp + (long)(dt * 16 + (lane & 15)) * SEQ + kt + (lane >> 4) * 8);
      oacc[dt] = __builtin_amdgcn_mfma_f32_16x16x32_bf16(pa, vb, oacc[dt], 0, 0, 0);
    }
    __syncthreads();
  }
  // epilogue: ctxb[b, s, h*64+d] bf16
#pragma unroll
  for (int dt = 0; dt < 4; ++dt)
#pragma unroll
    for (int r = 0; r < 4; ++r) {
      int s = q0 + wv * 16 + ((lane >> 4) << 2) + r;
      ctxb[((long)b * SEQ + s) * HDIM + h * 64 + dt * 16 + (lane & 15)] = f2bf(oacc[dt][r]);
    }
}

extern "C" void kernel_launch(void* const* d_in, const int* in_sizes, int n_in,
                              void* d_out, int out_size, void* d_ws, size_t ws_size,
                              hipStream_t stream) {
  const float* x  = (const float*)d_in[0];
  const float* cs = (const float*)d_in[1];
  const float* sn = (const float*)d_in[2];
  const float* Wq = (const float*)d_in[4];
  const float* Wk = (const float*)d_in[5];
  const float* Wv = (const float*)d_in[6];
  const float* Wo = (const float*)d_in[7];

  float* out = (float*)d_out;                   // [B,S,H] fp32
  float* aw  = out + (long)BATCH * SEQ * HDIM;  // [B,NH,S,S] fp32

  short* ws   = (short*)d_ws;
  short* xb   = ws;                              // [4096][2048]
  short* WqT  = xb  + (long)4096 * 2048;         // [2048][2048]
  short* WkT  = WqT + (long)2048 * 2048;         // [512][2048]
  short* WvT  = WkT + (long)512 * 2048;          // [512][2048]
  short* WoT  = WvT + (long)512 * 2048;          // [2048][2048]
  short* Qb   = WoT + (long)2048 * 2048;         // [4,32,1024,64]
  short* Kb2  = Qb  + (long)BATCH * NHQ * SEQ * 64;   // [4,8,1024,64]
  short* Vt   = Kb2 + (long)BATCH * NKV * SEQ * 64;   // [4,8,64,1024]
  short* ctxb = Vt  + (long)BATCH * NKV * SEQ * 64;   // [4096][2048]

  convx_k<<<(4096 * 2048) / (256 * 4), 256, 0, stream>>>(x, xb);
  wtrans_k<<<dim3(32, 32), 256, 0, stream>>>(Wq, WqT, 2048, 2048);
  wtrans_k<<<dim3(8, 32), 256, 0, stream>>>(Wk, WkT, 2048, 512);
  wtrans_k<<<dim3(8, 32), 256, 0, stream>>>(Wv, WvT, 2048, 512);
  wtrans_k<<<dim3(32, 32), 256, 0, stream>>>(Wo, WoT, 2048, 2048);

  gemm_k<<<dim3(16, 32), 256, 0, stream>>>(xb, WqT, Qb, 4096, 2048, 2048, 1, NHQ);
  gemm_k<<<dim3(4, 32), 256, 0, stream>>>(xb, WkT, Kb2, 4096, 512, 2048, 1, NKV);
  gemm_k<<<dim3(4, 32), 256, 0, stream>>>(xb, WvT, Vt, 4096, 512, 2048, 2, NKV);

  rope_k<<<BATCH * NHQ * SEQ, 64, 0, stream>>>(Qb, cs, sn, NHQ);
  rope_k<<<BATCH * NKV * SEQ, 64, 0, stream>>>(Kb2, cs, sn, NKV);

  scores_k<<<dim3(8, 8, BATCH * NHQ), 256, 0, stream>>>(Qb, Kb2, aw);
  smpv_k<<<dim3(16, BATCH * NHQ), 256, 0, stream>>>(aw, Vt, ctxb);

  gemm_k<<<dim3(16, 32), 256, 0, stream>>>(ctxb, WoT, out, 4096, 2048, 2048, 0, 0);
}

// Round 3
// 1060.875 us; speedup vs baseline: 2.6859x; 1.2741x over previous
//
#include <hip/hip_runtime.h>
#include <hip/hip_bf16.h>

#define NHQ 32
#define NKV 8
#define SEQ 1024
#define BATCH 4
#define HDIM 2048

typedef short bf16x8 __attribute__((ext_vector_type(8)));
typedef short short4v __attribute__((ext_vector_type(4)));
typedef float f32x4 __attribute__((ext_vector_type(4)));

__device__ __forceinline__ short f2bf(float f) {
  unsigned u = __builtin_bit_cast(unsigned, f);
  u += 0x7fff + ((u >> 16) & 1);
  return (short)(u >> 16);
}
__device__ __forceinline__ float bf2f(short s) {
  unsigned u = ((unsigned)(unsigned short)s) << 16;
  return __builtin_bit_cast(float, u);
}
__device__ __forceinline__ void gl2lds16(const void* g, void* l) {
  __builtin_amdgcn_global_load_lds(
      (const __attribute__((address_space(1))) unsigned int*)g,
      (__attribute__((address_space(3))) unsigned int*)l, 16, 0, 0);
}

// ---------- fp32 -> bf16 bulk convert (x) ----------
__global__ __launch_bounds__(256) void convx_k(
    const float* __restrict__ x, short* __restrict__ xb)
{
  long i = ((long)blockIdx.x * 256 + threadIdx.x) * 4;
  float4 v = *(const float4*)(x + i);
  short4v o = {f2bf(v.x), f2bf(v.y), f2bf(v.z), f2bf(v.w)};
  *(short4v*)(xb + i) = o;
}

// ---------- weight transpose fp32 [K][N] -> bf16 [N][K] ----------
__global__ __launch_bounds__(256) void wtrans_k(
    const float* __restrict__ W, short* __restrict__ WT, int K, int N)
{
  __shared__ float t[64][65];
  int k0 = blockIdx.y * 64, n0 = blockIdx.x * 64;
  int r = threadIdx.x >> 4, c = (threadIdx.x & 15) * 4;
#pragma unroll
  for (int it = 0; it < 4; ++it) {
    float4 v = *(const float4*)(W + (long)(k0 + r + it * 16) * N + n0 + c);
    t[c + 0][r + it * 16] = v.x;
    t[c + 1][r + it * 16] = v.y;
    t[c + 2][r + it * 16] = v.z;
    t[c + 3][r + it * 16] = v.w;
  }
  __syncthreads();
  int wr = threadIdx.x >> 2, wc = (threadIdx.x & 3) * 16;
#pragma unroll
  for (int u = 0; u < 4; ++u) {
    short4v o = {f2bf(t[wr][wc + u * 4 + 0]), f2bf(t[wr][wc + u * 4 + 1]),
                 f2bf(t[wr][wc + u * 4 + 2]), f2bf(t[wr][wc + u * 4 + 3])};
    *(short4v*)&WT[(long)(n0 + wr) * K + k0 + wc + u * 4] = o;
  }
}

// ---------- MFMA GEMM: C[M,N] = A[M,K] * BT[N,K]^T (bf16 in) ----------
// mode 0: C fp32 row-major; mode 1: C bf16 scatter [b,head,s,d];
// mode 2: C bf16 transpose-scatter [b,kvh,d,s]
__global__ __launch_bounds__(256) void gemm_k(
    const short* __restrict__ A, const short* __restrict__ BT,
    void* __restrict__ C, int M, int N, int K, int mode, int nheads)
{
  __shared__ short smA[128 * 32];
  __shared__ short smB[128 * 32];
  const int tid = threadIdx.x;
  const int lane = tid & 63, w = tid >> 6;
  const int wr = w >> 1, wc = w & 1;
  const int lm = lane & 15, lk = lane >> 4;
  const int row0 = blockIdx.y * 128, col0 = blockIdx.x * 128;
  const int c0 = tid, c1 = tid + 256;

  const short* Ab = A + (long)row0 * K;
  const short* Bb = BT + (long)col0 * K;

  f32x4 acc[4][4] = {};

  for (int k0 = 0; k0 < K; k0 += 32) {
    gl2lds16(Ab + (long)(c0 >> 2) * K + k0 + (c0 & 3) * 8, &smA[c0 * 8]);
    gl2lds16(Ab + (long)(c1 >> 2) * K + k0 + (c1 & 3) * 8, &smA[c1 * 8]);
    gl2lds16(Bb + (long)(c0 >> 2) * K + k0 + (c0 & 3) * 8, &smB[c0 * 8]);
    gl2lds16(Bb + (long)(c1 >> 2) * K + k0 + (c1 & 3) * 8, &smB[c1 * 8]);
    __syncthreads();
    bf16x8 af[4], bf[4];
#pragma unroll
    for (int i = 0; i < 4; ++i)
      af[i] = *(const bf16x8*)&smA[(wr * 64 + i * 16 + lm) * 32 + lk * 8];
#pragma unroll
    for (int j = 0; j < 4; ++j)
      bf[j] = *(const bf16x8*)&smB[(wc * 64 + j * 16 + lm) * 32 + lk * 8];
#pragma unroll
    for (int i = 0; i < 4; ++i)
#pragma unroll
      for (int j = 0; j < 4; ++j)
        acc[i][j] = __builtin_amdgcn_mfma_f32_16x16x32_bf16(af[i], bf[j], acc[i][j], 0, 0, 0);
    __syncthreads();
  }

#pragma unroll
  for (int i = 0; i < 4; ++i) {
    int grow = row0 + wr * 64 + i * 16 + lk * 4;
#pragma unroll
    for (int j = 0; j < 4; ++j) {
      int gcol = col0 + wc * 64 + j * 16 + lm;
      if (mode == 0) {
        float* Co = (float*)C;
#pragma unroll
        for (int r = 0; r < 4; ++r)
          Co[(long)(grow + r) * N + gcol] = acc[i][j][r];
      } else if (mode == 1) {
        short* Co = (short*)C;
        int h = gcol >> 6, d = gcol & 63;
#pragma unroll
        for (int r = 0; r < 4; ++r) {
          int row = grow + r;
          int b = row >> 10, s = row & 1023;
          Co[((long)(b * nheads + h) * SEQ + s) * 64 + d] = f2bf(acc[i][j][r]);
        }
      } else {
        short* Co = (short*)C;
        int kvh = gcol >> 6, d = gcol & 63;
        int b = grow >> 10, s0 = grow & 1023;
        short4v o = {f2bf(acc[i][j][0]), f2bf(acc[i][j][1]),
                     f2bf(acc[i][j][2]), f2bf(acc[i][j][3])};
        *(short4v*)&Co[((long)(b * NKV + kvh) * 64 + d) * SEQ + s0] = o;
      }
    }
  }
}

// ---------- RoPE in-place on bf16 [b,h,s,d], one wave per row ----------
__global__ __launch_bounds__(64) void rope_k(
    short* __restrict__ t, const float* __restrict__ cs,
    const float* __restrict__ sn, int nheads)
{
  long row = blockIdx.x;
  int d = threadIdx.x;
  int s = (int)(row & 1023);
  int b = (int)(row / ((long)nheads << 10));
  float v = bf2f(t[row * 64 + d]);
  float p = __shfl_xor(v, 32);
  float rh = (d < 32) ? -p : p;
  long ci = ((long)(b << 10) + s) * 64 + d;
  t[row * 64 + d] = f2bf(v * cs[ci] + rh * sn[ci]);
}

// ---------- fused scores+softmax+PV (flash-style, two-pass K loop) -------
// block = 256 thr = 4 waves; tile = 128 q-rows x (q0+128) k-cols, chunks of 64
// wave wv owns q-rows [q0+wv*32, q0+wv*32+32)
__global__ __launch_bounds__(256) void fattn_k(
    const short* __restrict__ Qb, const short* __restrict__ Kb,
    const short* __restrict__ Vt, float* __restrict__ aw,
    short* __restrict__ ctxb)
{
  __shared__ short Pl[4][32 * 72];  // per-wave P staging, stride 72
  const int bh = blockIdx.y;
  const int h = bh & 31, b = bh >> 5;
  const int q0 = blockIdx.x * 128;
  const int tid = threadIdx.x;
  const int lane = tid & 63, wv = tid >> 6;
  const int lm = lane & 15, lk = lane >> 4;

  const short* Qp = Qb + ((long)bh << 16);
  const short* Kp = Kb + ((long)(b * NKV + (h >> 2)) << 16);
  const short* Vp = Vt + ((long)(b * NKV + (h >> 2)) << 16);  // [64 d][1024 s]
  float* awb = aw + ((long)bh << 20);

  const int nch = (q0 >> 6) + 2;
  const int zc = nch * 64;  // first all-zero column

  // ---- zero-fill the fully-masked region [zc, 1024) ----
  if (zc < SEQ) {
    float4 z4 = make_float4(0.f, 0.f, 0.f, 0.f);
    for (int r = wv; r < 128; r += 4)
      for (int c = zc + lane * 4; c < SEQ; c += 256)
        *(float4*)(awb + (long)(q0 + r) * SEQ + c) = z4;
  }

  // ---- Q fragments (resident) ----
  bf16x8 qa[2][2];
#pragma unroll
  for (int i = 0; i < 2; ++i)
#pragma unroll
    for (int hf = 0; hf < 2; ++hf)
      qa[i][hf] = *(const bf16x8*)(Qp + (long)(q0 + wv * 32 + i * 16 + lm) * 64 + hf * 32 + lk * 8);

  float m[2][4], l[2][4];
#pragma unroll
  for (int i = 0; i < 2; ++i)
#pragma unroll
    for (int r = 0; r < 4; ++r) { m[i][r] = -3.0e38f; l[i][r] = 0.f; }

  // ---- pass 1: online row max / exp-sum ----
  for (int ch = 0; ch < nch; ++ch) {
    const int k0c = ch * 64;
    bf16x8 kb[4][2];
#pragma unroll
    for (int j = 0; j < 4; ++j)
#pragma unroll
      for (int hf = 0; hf < 2; ++hf)
        kb[j][hf] = *(const bf16x8*)(Kp + (long)(k0c + j * 16 + lm) * 64 + hf * 32 + lk * 8);
    f32x4 s[2][4] = {};
#pragma unroll
    for (int i = 0; i < 2; ++i)
#pragma unroll
      for (int j = 0; j < 4; ++j) {
        s[i][j] = __builtin_amdgcn_mfma_f32_16x16x32_bf16(qa[i][0], kb[j][0], s[i][j], 0, 0, 0);
        s[i][j] = __builtin_amdgcn_mfma_f32_16x16x32_bf16(qa[i][1], kb[j][1], s[i][j], 0, 0, 0);
      }
#pragma unroll
    for (int i = 0; i < 2; ++i)
#pragma unroll
      for (int r = 0; r < 4; ++r) {
        const int qi = q0 + wv * 32 + i * 16 + lk * 4 + r;
        float cm = -3.0e38f;
#pragma unroll
        for (int j = 0; j < 4; ++j) {
          float sv = s[i][j][r] * 0.125f;
          cm = (qi >= k0c + j * 16 + lm) ? fmaxf(cm, sv) : cm;
        }
#pragma unroll
        for (int off = 1; off <= 8; off <<= 1) cm = fmaxf(cm, __shfl_xor(cm, off));
        float mn = fmaxf(m[i][r], cm);
        float sum = 0.f;
#pragma unroll
        for (int j = 0; j < 4; ++j) {
          float sv = s[i][j][r] * 0.125f;
          sum += (qi >= k0c + j * 16 + lm) ? __expf(sv - mn) : 0.f;
        }
#pragma unroll
        for (int off = 1; off <= 8; off <<= 1) sum += __shfl_xor(sum, off);
        l[i][r] = l[i][r] * __expf(m[i][r] - mn) + sum;
        m[i][r] = mn;
      }
  }
#pragma unroll
  for (int i = 0; i < 2; ++i)
#pragma unroll
    for (int r = 0; r < 4; ++r) l[i][r] = 1.f / l[i][r];  // invl

  // ---- pass 2: recompute, normalize, write aw, PV-accumulate ----
  f32x4 oacc[2][4] = {};
  short* Pw = Pl[wv];
  for (int ch = 0; ch < nch; ++ch) {
    const int k0c = ch * 64;
    bf16x8 kb[4][2];
#pragma unroll
    for (int j = 0; j < 4; ++j)
#pragma unroll
      for (int hf = 0; hf < 2; ++hf)
        kb[j][hf] = *(const bf16x8*)(Kp + (long)(k0c + j * 16 + lm) * 64 + hf * 32 + lk * 8);
    f32x4 s[2][4] = {};
#pragma unroll
    for (int i = 0; i < 2; ++i)
#pragma unroll
      for (int j = 0; j < 4; ++j) {
        s[i][j] = __builtin_amdgcn_mfma_f32_16x16x32_bf16(qa[i][0], kb[j][0], s[i][j], 0, 0, 0);
        s[i][j] = __builtin_amdgcn_mfma_f32_16x16x32_bf16(qa[i][1], kb[j][1], s[i][j], 0, 0, 0);
      }
#pragma unroll
    for (int i = 0; i < 2; ++i)
#pragma unroll
      for (int j = 0; j < 4; ++j)
#pragma unroll
        for (int r = 0; r < 4; ++r) {
          const int qi = q0 + wv * 32 + i * 16 + lk * 4 + r;
          const int ki = k0c + j * 16 + lm;
          float p = (qi >= ki) ? __expf(s[i][j][r] * 0.125f - m[i][r]) * l[i][r] : 0.f;
          awb[(long)qi * SEQ + ki] = p;
          Pw[(i * 16 + lk * 4 + r) * 72 + j * 16 + lm] = f2bf(p);
        }
    __syncthreads();
#pragma unroll
    for (int i = 0; i < 2; ++i) {
      bf16x8 pa0 = *(const bf16x8*)&Pw[(i * 16 + lm) * 72 + lk * 8];
      bf16x8 pa1 = *(const bf16x8*)&Pw[(i * 16 + lm) * 72 + 32 + lk * 8];
#pragma unroll
      for (int dt = 0; dt < 4; ++dt) {
        bf16x8 vb0 = *(const bf16x8*)(Vp + (long)(dt * 16 + lm) * SEQ + k0c + lk * 8);
        bf16x8 vb1 = *(const bf16x8*)(Vp + (long)(dt * 16 + lm) * SEQ + k0c + 32 + lk * 8);
        oacc[i][dt] = __builtin_amdgcn_mfma_f32_16x16x32_bf16(pa0, vb0, oacc[i][dt], 0, 0, 0);
        oacc[i][dt] = __builtin_amdgcn_mfma_f32_16x16x32_bf16(pa1, vb1, oacc[i][dt], 0, 0, 0);
      }
    }
    __syncthreads();
  }

  // ---- epilogue: ctxb[b, s, h*64+d] bf16 ----
#pragma unroll
  for (int i = 0; i < 2; ++i)
#pragma unroll
    for (int dt = 0; dt < 4; ++dt)
#pragma unroll
      for (int r = 0; r < 4; ++r) {
        int srow = q0 + wv * 32 + i * 16 + lk * 4 + r;
        ctxb[((long)b * SEQ + srow) * HDIM + h * 64 + dt * 16 + lm] = f2bf(oacc[i][dt][r]);
      }
}

extern "C" void kernel_launch(void* const* d_in, const int* in_sizes, int n_in,
                              void* d_out, int out_size, void* d_ws, size_t ws_size,
                              hipStream_t stream) {
  const float* x  = (const float*)d_in[0];
  const float* cs = (const float*)d_in[1];
  const float* sn = (const float*)d_in[2];
  const float* Wq = (const float*)d_in[4];
  const float* Wk = (const float*)d_in[5];
  const float* Wv = (const float*)d_in[6];
  const float* Wo = (const float*)d_in[7];

  float* out = (float*)d_out;                   // [B,S,H] fp32
  float* aw  = out + (long)BATCH * SEQ * HDIM;  // [B,NH,S,S] fp32

  short* ws   = (short*)d_ws;
  short* xb   = ws;                              // [4096][2048]
  short* WqT  = xb  + (long)4096 * 2048;
  short* WkT  = WqT + (long)2048 * 2048;
  short* WvT  = WkT + (long)512 * 2048;
  short* WoT  = WvT + (long)512 * 2048;
  short* Qb   = WoT + (long)2048 * 2048;         // [4,32,1024,64]
  short* Kb2  = Qb  + (long)BATCH * NHQ * SEQ * 64;   // [4,8,1024,64]
  short* Vt   = Kb2 + (long)BATCH * NKV * SEQ * 64;   // [4,8,64,1024]
  short* ctxb = Vt  + (long)BATCH * NKV * SEQ * 64;   // [4096][2048]

  convx_k<<<(4096 * 2048) / (256 * 4), 256, 0, stream>>>(x, xb);
  wtrans_k<<<dim3(32, 32), 256, 0, stream>>>(Wq, WqT, 2048, 2048);
  wtrans_k<<<dim3(8, 32), 256, 0, stream>>>(Wk, WkT, 2048, 512);
  wtrans_k<<<dim3(8, 32), 256, 0, stream>>>(Wv, WvT, 2048, 512);
  wtrans_k<<<dim3(32, 32), 256, 0, stream>>>(Wo, WoT, 2048, 2048);

  gemm_k<<<dim3(16, 32), 256, 0, stream>>>(xb, WqT, Qb, 4096, 2048, 2048, 1, NHQ);
  gemm_k<<<dim3(4, 32), 256, 0, stream>>>(xb, WkT, Kb2, 4096, 512, 2048, 1, NKV);
  gemm_k<<<dim3(4, 32), 256, 0, stream>>>(xb, WvT, Vt, 4096, 512, 2048, 2, NKV);

  rope_k<<<BATCH * NHQ * SEQ, 64, 0, stream>>>(Qb, cs, sn, NHQ);
  rope_k<<<BATCH * NKV * SEQ, 64, 0, stream>>>(Kb2, cs, sn, NKV);

  fattn_k<<<dim3(8, BATCH * NHQ), 256, 0, stream>>>(Qb, Kb2, Vt, aw, ctxb);

  gemm_k<<<dim3(16, 32), 256, 0, stream>>>(ctxb, WoT, out, 4096, 2048, 2048, 0, 0);
}